// Round 2
// baseline (2651.815 us; speedup 1.0000x reference)
//
#include <hip/hip_runtime.h>
#include <cstdint>

__device__ __forceinline__ float clamp01f(float v) { return fminf(fmaxf(v, 0.0f), 1.0f); }

// ======================= edge sort by dst (CSR build) =======================
__global__ __launch_bounds__(256) void edge_count_kernel(
    const int* __restrict__ edst, int* __restrict__ cnt, int E)
{
    int e = blockIdx.x * 256 + threadIdx.x;
    if (e < E) atomicAdd(&cnt[edst[e]], 1);
}

__global__ __launch_bounds__(256) void edge_scatter_kernel(
    const int* __restrict__ esrc, const int* __restrict__ edst,
    int* __restrict__ off, int* __restrict__ srcs, int E)
{
    int e = blockIdx.x * 256 + threadIdx.x;
    if (e >= E) return;
    int slot = atomicAdd(&off[edst[e]], 1);
    srcs[slot] = esrc[e];
}

// exclusive scan (scalar, baseline-proven); after edge_scatter, off[v] = segment END
__global__ __launch_bounds__(1024) void scan_kernel(
    const int* __restrict__ cnt, int* __restrict__ off, int Vc)
{
    __shared__ int s_sums[1024];
    const int t = threadIdx.x;
    const int chunk = (Vc + 1023) / 1024;
    const int b0 = min(t * chunk, Vc), b1 = min(b0 + chunk, Vc);
    int s = 0;
    for (int i = b0; i < b1; ++i) s += cnt[i];
    s_sums[t] = s;
    __syncthreads();
    for (int d = 1; d < 1024; d <<= 1) {
        int v = (t >= d) ? s_sums[t - d] : 0;
        __syncthreads();
        s_sums[t] += v;
        __syncthreads();
    }
    int base = (t == 0) ? 0 : s_sums[t - 1];
    for (int i = b0; i < b1; ++i) { off[i] = base; base += cnt[i]; }
}

// ======================= Layer-1 fused gather-reduce (CIN=3 -> COUT=16) =======
// thread (v,c): loops in-edges, computes basis+message in-register, epilogue fused.
__global__ __launch_bounds__(256) void l1_fused_kernel(
    const int* __restrict__ off, const int* __restrict__ cnt, const int* __restrict__ srcs,
    const float* __restrict__ pos, const float* __restrict__ x,
    const float* __restrict__ Wk, const float* __restrict__ Wr,
    const float* __restrict__ bias, float* __restrict__ out,
    float inv2mv, int V)
{
    int g = blockIdx.x * 256 + threadIdx.x;
    if (g >= V * 16) return;
    const int v = g >> 4, c = g & 15;
    float w[8][3];
#pragma unroll
    for (int s8 = 0; s8 < 8; ++s8)
#pragma unroll
        for (int ci = 0; ci < 3; ++ci)
            w[s8][ci] = Wk[s8 * 48 + ci * 16 + c];
    const float pdx = pos[v * 3 + 0], pdy = pos[v * 3 + 1], pdt = pos[v * 3 + 2];
    const int e1 = off[v];
    const int n = cnt[v];
    float acc = 0.f;
    int j = e1 - n;
    for (; j + 1 < e1; j += 2) {
        int sa = srcs[j], sb = srcs[j + 1];
        float pax = pos[sa * 3 + 0], pay = pos[sa * 3 + 1], pat = pos[sa * 3 + 2];
        float pbx = pos[sb * 3 + 0], pby = pos[sb * 3 + 1], pbt = pos[sb * 3 + 2];
        float xa = x[sa], xb = x[sb];
        {
            float p0 = clamp01f((pdx - pax) * inv2mv + 0.5f);
            float p1 = clamp01f((pdy - pay) * inv2mv + 0.5f);
            float p2 = clamp01f((pdt - pat) * inv2mv + 0.5f);
            float q0 = 1.f - p0, q1 = 1.f - p1, q2 = 1.f - p2;
#pragma unroll
            for (int s8 = 0; s8 < 8; ++s8) {
                float b = ((s8 & 1) ? p0 : q0) * ((s8 & 2) ? p1 : q1) * ((s8 & 4) ? p2 : q2);
                acc += b * (xa * w[s8][0] + pax * w[s8][1] + pay * w[s8][2]);
            }
        }
        {
            float p0 = clamp01f((pdx - pbx) * inv2mv + 0.5f);
            float p1 = clamp01f((pdy - pby) * inv2mv + 0.5f);
            float p2 = clamp01f((pdt - pbt) * inv2mv + 0.5f);
            float q0 = 1.f - p0, q1 = 1.f - p1, q2 = 1.f - p2;
#pragma unroll
            for (int s8 = 0; s8 < 8; ++s8) {
                float b = ((s8 & 1) ? p0 : q0) * ((s8 & 2) ? p1 : q1) * ((s8 & 4) ? p2 : q2);
                acc += b * (xb * w[s8][0] + pbx * w[s8][1] + pby * w[s8][2]);
            }
        }
    }
    if (j < e1) {
        int s = srcs[j];
        float psx = pos[s * 3 + 0], psy = pos[s * 3 + 1], pst = pos[s * 3 + 2];
        float xs = x[s];
        float p0 = clamp01f((pdx - psx) * inv2mv + 0.5f);
        float p1 = clamp01f((pdy - psy) * inv2mv + 0.5f);
        float p2 = clamp01f((pdt - pst) * inv2mv + 0.5f);
        float q0 = 1.f - p0, q1 = 1.f - p1, q2 = 1.f - p2;
#pragma unroll
        for (int s8 = 0; s8 < 8; ++s8) {
            float b = ((s8 & 1) ? p0 : q0) * ((s8 & 2) ? p1 : q1) * ((s8 & 4) ? p2 : q2);
            acc += b * (xs * w[s8][0] + psx * w[s8][1] + psy * w[s8][2]);
        }
    }
    float r = acc / fmaxf((float)n, 1.0f)
            + x[v] * Wr[c] + pdx * Wr[16 + c] + pdy * Wr[32 + c] + bias[c];
    out[g] = fmaxf(r, 0.0f);
}

// ======================= Tiled edge "GEMM" (layer 2, unchanged) =======================
template<int CIN, int COUT>
__global__ __launch_bounds__(256) void edge_gemm_kernel(
    const int* __restrict__ esrc, const int* __restrict__ edst,
    const float* __restrict__ pos, const float* __restrict__ hcat,
    const float* __restrict__ Wk,
    float* __restrict__ agg, float* __restrict__ deg, float inv2mv)
{
    constexpr int NJ = COUT / 32;
    __shared__ float s_basis[32 * 8];
    __shared__ __align__(16) float s_xs[32 * CIN];
    __shared__ float s_B[CIN * COUT];
    __shared__ int s_src[32];
    __shared__ int s_dst[32];
    const int tid = threadIdx.x;
    const int ebase = blockIdx.x * 32;
    if (tid < 32) {
        int e = ebase + tid;
        int s = esrc[e];
        int d = edst[e];
        s_src[tid] = s; s_dst[tid] = d;
        float p0 = clamp01f((pos[d * 3 + 0] - pos[s * 3 + 0]) * inv2mv + 0.5f);
        float p1 = clamp01f((pos[d * 3 + 1] - pos[s * 3 + 1]) * inv2mv + 0.5f);
        float p2 = clamp01f((pos[d * 3 + 2] - pos[s * 3 + 2]) * inv2mv + 0.5f);
        float q0 = 1.f - p0, q1 = 1.f - p1, q2 = 1.f - p2;
#pragma unroll
        for (int s8 = 0; s8 < 8; ++s8)
            s_basis[tid * 8 + s8] = ((s8 & 1) ? p0 : q0) * ((s8 & 2) ? p1 : q1) * ((s8 & 4) ? p2 : q2);
    }
    __syncthreads();
    for (int idx = tid; idx < 32 * CIN; idx += 256) {
        int e = idx / CIN, ci = idx - e * CIN;
        s_xs[idx] = hcat[s_src[e] * CIN + ci];
    }
    const int ty = tid >> 5, tx = tid & 31;
    float acc[4][NJ];
#pragma unroll
    for (int i = 0; i < 4; ++i)
#pragma unroll
        for (int j = 0; j < NJ; ++j) acc[i][j] = 0.f;

    for (int s8 = 0; s8 < 8; ++s8) {
        __syncthreads();
        for (int idx = tid; idx < CIN * COUT; idx += 256)
            s_B[idx] = Wk[s8 * CIN * COUT + idx];
        __syncthreads();
        float bas[4];
#pragma unroll
        for (int i = 0; i < 4; ++i) bas[i] = s_basis[(ty + i * 8) * 8 + s8];
#pragma unroll
        for (int c2 = 0; c2 < CIN; c2 += 2) {
            float2 a2[4];
#pragma unroll
            for (int i = 0; i < 4; ++i)
                a2[i] = *(const float2*)&s_xs[(ty + i * 8) * CIN + c2];
#pragma unroll
            for (int kk = 0; kk < 2; ++kk) {
                float b[NJ];
#pragma unroll
                for (int j = 0; j < NJ; ++j) b[j] = s_B[(c2 + kk) * COUT + tx + j * 32];
#pragma unroll
                for (int i = 0; i < 4; ++i) {
                    float a = bas[i] * (kk ? a2[i].y : a2[i].x);
#pragma unroll
                    for (int j = 0; j < NJ; ++j) acc[i][j] += a * b[j];
                }
            }
        }
    }
#pragma unroll
    for (int i = 0; i < 4; ++i) {
        int d = s_dst[ty + i * 8];
#pragma unroll
        for (int j = 0; j < NJ; ++j)
            atomicAdd(&agg[d * COUT + tx + j * 32], acc[i][j]);
        if (tx == 0) atomicAdd(&deg[d], 1.0f);
    }
}

// ======================= z precompute: z[v, s, c] = hcat[v] @ Wk[s] =======================
template<int CIN, int COUT, int TV>
__global__ __launch_bounds__(256) void z_node_kernel(
    const float* __restrict__ hcat, const float* __restrict__ Wk,
    float* __restrict__ z, int V)
{
    int g = blockIdx.x * 256 + threadIdx.x;
    int c = g % COUT;
    int s8 = (g / COUT) & 7;
    int vb = g / (COUT * 8);
    int v0 = vb * TV;
    if (v0 >= V) return;
    const float* w = Wk + s8 * CIN * COUT + c;
    float acc[TV];
#pragma unroll
    for (int t = 0; t < TV; ++t) acc[t] = 0.f;
    for (int ci = 0; ci < CIN; ++ci) {
        float wv = w[ci * COUT];
#pragma unroll
        for (int t = 0; t < TV; ++t)
            acc[t] += hcat[(v0 + t) * CIN + ci] * wv;
    }
#pragma unroll
    for (int t = 0; t < TV; ++t)
        z[(size_t)(v0 + t) * (8 * COUT) + s8 * COUT + c] = acc[t];
}

// ======================= z-based fused gather-reduce + epilogue (layers 3-5) =======
// thread (v,c): sequential reduce over dst-sorted in-edges, zero atomics, fused node out.
template<int COUT>
__global__ __launch_bounds__(256) void z_fused_kernel(
    const int* __restrict__ off, const int* __restrict__ cnt, const int* __restrict__ srcs,
    const float* __restrict__ pos, const float* __restrict__ z,
    const float* __restrict__ hcat, const float* __restrict__ Wr,
    const float* __restrict__ bias, float* __restrict__ out,
    float inv2mv, int V, int CIN)
{
    int g = blockIdx.x * 256 + threadIdx.x;
    if (g >= V * COUT) return;
    const int v = g / COUT, c = g % COUT;
    const float pdx = pos[v * 3 + 0], pdy = pos[v * 3 + 1], pdt = pos[v * 3 + 2];
    const int e1 = off[v];
    const int n = cnt[v];
    float acc = 0.f;
    for (int j = e1 - n; j < e1; ++j) {
        int s = srcs[j];
        float p0 = clamp01f((pdx - pos[s * 3 + 0]) * inv2mv + 0.5f);
        float p1 = clamp01f((pdy - pos[s * 3 + 1]) * inv2mv + 0.5f);
        float p2 = clamp01f((pdt - pos[s * 3 + 2]) * inv2mv + 0.5f);
        float q0 = 1.f - p0, q1 = 1.f - p1, q2 = 1.f - p2;
        const float* zp = z + (size_t)s * (8 * COUT) + c;
        float z0 = zp[0],        z1 = zp[COUT],     z2 = zp[2 * COUT], z3 = zp[3 * COUT];
        float z4 = zp[4 * COUT], z5 = zp[5 * COUT], z6 = zp[6 * COUT], z7 = zp[7 * COUT];
        float m = q0 * q1 * q2 * z0 + p0 * q1 * q2 * z1
                + q0 * p1 * q2 * z2 + p0 * p1 * q2 * z3
                + q0 * q1 * p2 * z4 + p0 * q1 * p2 * z5
                + q0 * p1 * p2 * z6 + p0 * p1 * p2 * z7;
        acc += m;
    }
    float r = bias[c];
    const float* hv = hcat + (size_t)v * CIN;
    for (int ci = 0; ci < CIN; ++ci)
        r += hv[ci] * Wr[ci * COUT + c];
    r += acc / fmaxf((float)n, 1.0f);
    out[g] = fmaxf(r, 0.0f);
}

// ======================= generic node epilogue (layer 2 only) =======================
template<int CIN, int COUT>
__global__ __launch_bounds__(256) void node_out_kernel(
    const float* __restrict__ agg, const float* __restrict__ deg,
    const float* __restrict__ hcat, const float* __restrict__ Wr,
    const float* __restrict__ bias, float* __restrict__ out, int V)
{
    int g = blockIdx.x * 256 + threadIdx.x;
    if (g >= V * COUT) return;
    int c = g % COUT;
    int v = g / COUT;
    float acc = bias[c];
    const float* hv = hcat + (size_t)v * CIN;
    for (int ci = 0; ci < CIN; ++ci)
        acc += hv[ci] * Wr[ci * COUT + c];
    float r = agg[g] / fmaxf(deg[v], 1.0f) + acc;
    out[g] = fmaxf(r, 0.0f);
}

// ======================= voxel pooling: counting-sort + copy + sequential reduce =====
__global__ __launch_bounds__(256) void pool_cluster_kernel(
    const float* __restrict__ pos, const int* __restrict__ batch, int bdiv, int V,
    int nx, int ny, int nt, int* __restrict__ cl, int* __restrict__ cnt)
{
    int n = blockIdx.x * 256 + threadIdx.x;
    if (n >= V) return;
    int b = batch ? batch[n] : (n / bdiv);
    float px = pos[n * 3 + 0], py = pos[n * 3 + 1], pt = pos[n * 3 + 2];
    int ix = (int)floorf(px * (float)nx); ix = min(max(ix, 0), nx - 1);
    int iy = (int)floorf(py * (float)ny); iy = min(max(iy, 0), ny - 1);
    int it = (int)floorf(pt * (float)nt); it = min(max(it, 0), nt - 1);
    int c = ((b * nx + ix) * ny + iy) * nt + it;
    cl[n] = c;
    atomicAdd(&cnt[c], 1);
}

__global__ __launch_bounds__(256) void pool_scatter_kernel(
    const int* __restrict__ cl, int* __restrict__ off, int* __restrict__ order, int V)
{
    int n = blockIdx.x * 256 + threadIdx.x;
    if (n >= V) return;
    int slot = atomicAdd(&off[cl[n]], 1);
    order[slot] = n;
}

template<int COUT>
__global__ __launch_bounds__(256) void pool_copy_kernel(
    const int* __restrict__ order, const float* __restrict__ h,
    const float* __restrict__ pos,
    float* __restrict__ S, float* __restrict__ Spos, int V)
{
    int g = blockIdx.x * 256 + threadIdx.x;
    if (g >= V * COUT) return;
    int slot = g / COUT;
    int c = g % COUT;
    int n = order[slot];
    S[g] = h[(size_t)n * COUT + c];
    if (c < 3) Spos[slot * 3 + c] = pos[n * 3 + c];
}

template<int COUT, int DOMEAN>
__global__ __launch_bounds__(256) void pool_reduce_kernel(
    const int* __restrict__ off, const int* __restrict__ cnt,
    const float* __restrict__ S, const float* __restrict__ Spos,
    float* __restrict__ hnext, float* __restrict__ pos_out, int Vc)
{
    const int g = blockIdx.x * 256 + threadIdx.x;
    if (g >= Vc * COUT) return;
    const int v = g / COUT;
    const int c = g % COUT;
    const int e1 = off[v];
    const int n0 = e1 - cnt[v];
    float acc = 0.0f;
    float ps = 0.0f;
    int j = n0;
    for (; j + 3 < e1; j += 4) {
        float a0 = S[(size_t)(j + 0) * COUT + c];
        float a1 = S[(size_t)(j + 1) * COUT + c];
        float a2 = S[(size_t)(j + 2) * COUT + c];
        float a3 = S[(size_t)(j + 3) * COUT + c];
        if (DOMEAN) acc += (a0 + a1) + (a2 + a3);
        else        acc = fmaxf(acc, fmaxf(fmaxf(a0, a1), fmaxf(a2, a3)));
        if (c < 3) {
            float p0 = Spos[(j + 0) * 3 + c];
            float p1 = Spos[(j + 1) * 3 + c];
            float p2 = Spos[(j + 2) * 3 + c];
            float p3 = Spos[(j + 3) * 3 + c];
            ps += (p0 + p1) + (p2 + p3);
        }
    }
    for (; j < e1; ++j) {
        float a0 = S[(size_t)j * COUT + c];
        acc = DOMEAN ? (acc + a0) : fmaxf(acc, a0);
        if (c < 3) ps += Spos[j * 3 + c];
    }
    float m = fmaxf((float)cnt[v], 1.0f);
    float* hp = hnext + (size_t)v * (COUT + 2);
    hp[c] = DOMEAN ? (acc / m) : acc;
    if (c < 3) {
        float pm = ps / m;
        pos_out[v * 3 + c] = pm;
        if (c < 2) hp[COUT + c] = pm;
    }
}

// ======================= host =======================
extern "C" void kernel_launch(void* const* d_in, const int* in_sizes, int n_in,
                              void* d_out, int out_size, void* d_ws, size_t ws_size,
                              hipStream_t stream)
{
    (void)in_sizes; (void)n_in; (void)out_size;
    const float* x    = (const float*)d_in[0];
    const float* pos0 = (const float*)d_in[1];
    const int*   bat  = (const int*)d_in[2];
    const int* e1 = (const int*)d_in[3];
    const int* e2 = (const int*)d_in[4];
    const int* e3 = (const int*)d_in[5];
    const int* e4 = (const int*)d_in[6];
    const int* e5 = (const int*)d_in[7];
    const float* W1 = (const float*)d_in[8],  *R1 = (const float*)d_in[9],  *B1 = (const float*)d_in[10];
    const float* W2 = (const float*)d_in[11], *R2 = (const float*)d_in[12], *B2 = (const float*)d_in[13];
    const float* W3 = (const float*)d_in[14], *R3 = (const float*)d_in[15], *B3 = (const float*)d_in[16];
    const float* W4 = (const float*)d_in[17], *R4 = (const float*)d_in[18], *B4 = (const float*)d_in[19];
    const float* W5 = (const float*)d_in[20], *R5 = (const float*)d_in[21], *B5 = (const float*)d_in[22];

    const int E1 = 3600000, E2 = 786432, E3 = 196608, E4 = 24576, E5 = 3072;

    if (ws_size < (size_t)21800000 * sizeof(float)) return;
    float* ws   = (float*)d_ws;
    float* AGG  = ws;             // cap 6,400,000: edge-sort CSR ints / L2 agg+deg / pooling S / h3
    float* BZ   = ws + 6400000;   // cap 12,600,000: h_i / z_{i+1}; pooling scratch after live extent
    float* HC   = ws + 19000000;  // cap 1,800,000: hcat of current graph
    float* POSA = ws + 20800000;
    float* POSB = ws + 21100000;

    float* out3 = (float*)d_out;           // 1536*128
    float* hfin = (float*)d_out + 196608;  // 192*128

#define MS(p, nfl) hipMemsetAsync((p), 0, (size_t)(nfl) * sizeof(float), stream)

    // Build in-edge CSR for edge list ep (src = ep[0:En], dst = ep[En:2En]) over Vn nodes.
    // Declares cnt_/off_/src_ locals in AGG; off_[v] = segment END after scatter.
#define ESORT(ep, En, Vn)                                                                        \
    int* cnt_ = (int*)AGG;                                                                       \
    int* off_ = cnt_ + (Vn);                                                                     \
    int* src_ = off_ + (Vn);                                                                     \
    hipMemsetAsync(cnt_, 0, (size_t)(Vn) * sizeof(int), stream);                                 \
    edge_count_kernel<<<((En) + 255) / 256, 256, 0, stream>>>((ep) + (En), cnt_, En);            \
    scan_kernel<<<1, 1024, 0, stream>>>(cnt_, off_, Vn);                                         \
    edge_scatter_kernel<<<((En) + 255) / 256, 256, 0, stream>>>((ep), (ep) + (En), off_, src_, En)

#define POOL(hsrc, possrc, batp, bdiv, Vn, NX, NY, NT, COUTV, DM, hdst, posdst, off_free)   \
    {                                                                                       \
        int Vc = 4 * (NX) * (NY) * (NT);                                                    \
        float* SF   = AGG;                                                                  \
        float* SPOS = BZ + (off_free);                                                      \
        int* ICL  = (int*)(SPOS + (size_t)(Vn) * 3);                                        \
        int* IORD = ICL + (Vn);                                                             \
        int* ICNT = IORD + (Vn);                                                            \
        int* IOFF = ICNT + Vc;                                                              \
        hipMemsetAsync(ICNT, 0, (size_t)Vc * sizeof(int), stream);                          \
        pool_cluster_kernel<<<((Vn) + 255) / 256, 256, 0, stream>>>(                        \
            possrc, batp, bdiv, Vn, NX, NY, NT, ICL, ICNT);                                 \
        scan_kernel<<<1, 1024, 0, stream>>>(ICNT, IOFF, Vc);                                \
        pool_scatter_kernel<<<((Vn) + 255) / 256, 256, 0, stream>>>(ICL, IOFF, IORD, Vn);   \
        pool_copy_kernel<COUTV><<<((Vn) * (COUTV) + 255) / 256, 256, 0, stream>>>(          \
            IORD, hsrc, possrc, SF, SPOS, Vn);                                              \
        pool_reduce_kernel<COUTV, DM><<<(Vc * (COUTV) + 255) / 256, 256, 0, stream>>>(      \
            IOFF, ICNT, SF, SPOS, hdst, posdst, Vc);                                        \
    }

    // ---------- Layer 1: 300000 nodes, CIN=3, COUT=16 — sorted gather-reduce, no atomics ----------
    {
        ESORT(e1, E1, 300000);   // ints: 300000+300000+3600000 = 4.2M in AGG
        l1_fused_kernel<<<(300000 * 16) / 256, 256, 0, stream>>>(
            off_, cnt_, src_, pos0, x, W1, R1, B1, BZ, 20.0f, 300000);
        // h1 at BZ occupies 4.8M floats -> pooling scratch at BZ+4.8M; SF=AGG (sort ints dead)
        POOL(BZ, pos0, bat, 0, 300000, 64, 48, 8, 16, 0, HC, POSA, 4800000);
    }
    // ---------- Layer 2: 98304 nodes, CIN=18, COUT=64 (unchanged atomic path) ----------
    {
        float* agg = AGG; float* deg = AGG + 6291456;
        MS(agg, 6291456 + 98304);
        edge_gemm_kernel<18, 64><<<E2 / 32, 256, 0, stream>>>(e2, e2 + E2, POSA, HC, W2, agg, deg, 10.0f);
        node_out_kernel<18, 64><<<(98304 * 64) / 256, 256, 0, stream>>>(agg, deg, HC, R2, B2, BZ, 98304);
        POOL(BZ, POSA, nullptr, 24576, 98304, 32, 24, 4, 64, 0, HC, POSB, 6291456);
    }
    // ---------- Layer 3: 12288 nodes, CIN=66, COUT=128 (z path, fused reduce) ----------
    {
        z_node_kernel<66, 128, 8><<<(12288 / 8) * 1024 / 256, 256, 0, stream>>>(HC, W3, BZ, 12288);
        ESORT(e3, E3, 12288);    // ints: 221184 in AGG
        float* h3 = AGG + 4800000;  // 1.57M floats, disjoint from sort ints
        z_fused_kernel<128><<<(12288 * 128) / 256, 256, 0, stream>>>(
            off_, cnt_, src_, POSB, BZ, HC, R3, B3, h3, 6.0f, 12288, 66);
        // z3 in BZ dead now -> pooling scratch at BZ+0; SF=AGG[0..1.57M] disjoint from h3
        POOL(h3, POSB, nullptr, 3072, 12288, 16, 12, 2, 128, 0, HC, POSA, 0);
    }
    // ---------- Layer 4: 1536 nodes, CIN=130, COUT=128 (z path, fused) -> out3 ----------
    {
        z_node_kernel<130, 128, 8><<<(1536 / 8) * 1024 / 256, 256, 0, stream>>>(HC, W4, BZ, 1536);
        ESORT(e4, E4, 1536);
        z_fused_kernel<128><<<(1536 * 128) / 256, 256, 0, stream>>>(
            off_, cnt_, src_, POSA, BZ, HC, R4, B4, out3, 3.0f, 1536, 130);
        POOL(out3, POSA, nullptr, 384, 1536, 8, 6, 1, 128, 1, HC, POSB, 0);
    }
    // ---------- Layer 5: 192 nodes, CIN=130, COUT=128 (z path, fused) -> hfin ----------
    {
        z_node_kernel<130, 128, 8><<<(192 / 8) * 1024 / 256, 256, 0, stream>>>(HC, W5, BZ, 192);
        ESORT(e5, E5, 192);
        z_fused_kernel<128><<<(192 * 128) / 256, 256, 0, stream>>>(
            off_, cnt_, src_, POSB, BZ, HC, R5, B5, hfin, 1.5f, 192, 130);
    }
#undef POOL
#undef ESORT
#undef MS
}